// Round 7
// baseline (133.613 us; speedup 1.0000x reference)
//
#include <hip/hip_runtime.h>
#include <math.h>

// Tropical (max-plus) matmul: out[b,o] = max_k ( x[b,k] + W[o,k] )
// x: (2048,512) f32, W: (512,512) f32, out: (2048,512) f32.
//
// R9 post-mortem: exact candidate pruning won (93.4 -> 65.3us, absmax 0).
// Top dispatches are now the harness's fixed ~42us/268MB ws re-poison.
// Controllable residual ~23us = prep + sparse (serialized) + dispatch
// overhead.
// R10: fuse prep+sparse into ONE kernel with a device-scope release/
// acquire gate (4B flag zeroed by hipMemsetAsync). Blocks 0..63 do the
// W transpose + min/max (phase A); ALL 512 blocks preload their x rows
// and row-max BEFORE the gate (x latency hides under phase A), spin on
// the flag, then run the candidate phase. Deadlock-safe by capacity:
// >=4 blocks/CU possible vs 2/CU needed -> all 512 co-resident.

#define B_ROWS 2048
#define K_DIM  512
#define O_DIM  512

// ws float layout: [0] flag (memset to 0) | [2..129] 64 (min,max) pairs
// | Wt (512x512) at float offset 2304 (16B aligned).
#define WS_PAIRS 2
#define WS_WT    2304
#define WS_NEED_BYTES ((size_t)(WS_WT + K_DIM * O_DIM) * sizeof(float))
#define NWORK 64u

__global__ __launch_bounds__(256) void tropical_fused(
    const float* __restrict__ x, const float* __restrict__ W,
    float* __restrict__ ws, float* __restrict__ out)
{
    __shared__ float sm[64][65];      // transpose tile, padded
    __shared__ float wmin4[4], wmax4[4];

    const int t  = threadIdx.x;
    const int bx = blockIdx.x;
    unsigned int* flag = (unsigned int*)ws;
    float* Wt = ws + WS_WT;

    // ---- phase A: blocks 0..63 transpose W and publish block min/max ----
    if (bx < 64) {
        const int tr  = (bx >> 3) * 64;   // o-dim tile base
        const int tc  = (bx & 7) * 64;    // k-dim tile base
        const int lr0 = t >> 4;           // 0..15
        const int lc  = (t & 15) * 4;     // 0..60

        float lmin = INFINITY, lmax = -INFINITY;
#pragma unroll
        for (int q = 0; q < 4; ++q) {
            const int r = lr0 + q * 16;
            float4 v = *(const float4*)(W + (size_t)(tr + r) * K_DIM + tc + lc);
            sm[r][lc + 0] = v.x; sm[r][lc + 1] = v.y;
            sm[r][lc + 2] = v.z; sm[r][lc + 3] = v.w;
            lmin = fminf(lmin, fminf(fminf(v.x, v.y), fminf(v.z, v.w)));
            lmax = fmaxf(lmax, fmaxf(fmaxf(v.x, v.y), fmaxf(v.z, v.w)));
        }
        __syncthreads();
#pragma unroll
        for (int q = 0; q < 4; ++q) {
            const int kr = lr0 + q * 16;
            float4 v;
            v.x = sm[lc + 0][kr]; v.y = sm[lc + 1][kr];
            v.z = sm[lc + 2][kr]; v.w = sm[lc + 3][kr];
            *(float4*)(Wt + (size_t)(tc + kr) * O_DIM + tr + lc) = v;
        }
#pragma unroll
        for (int off = 32; off; off >>= 1) {
            lmin = fminf(lmin, __shfl_xor(lmin, off));
            lmax = fmaxf(lmax, __shfl_xor(lmax, off));
        }
        if ((t & 63) == 0) { wmin4[t >> 6] = lmin; wmax4[t >> 6] = lmax; }
        __syncthreads();
        if (t == 0) {
            ws[WS_PAIRS + 2 * bx] =
                fminf(fminf(wmin4[0], wmin4[1]), fminf(wmin4[2], wmin4[3]));
            ws[WS_PAIRS + 2 * bx + 1] =
                fmaxf(fmaxf(wmax4[0], wmax4[1]), fmaxf(wmax4[2], wmax4[3]));
        }
        __threadfence();                  // all this block's ws writes visible
        __syncthreads();
        if (t == 0)
            __hip_atomic_fetch_add(flag, 1u, __ATOMIC_RELEASE,
                                   __HIP_MEMORY_SCOPE_AGENT);
    }

    // ---- phase B preamble (ALL blocks, before the gate): load x row ----
    const int w    = t >> 6;              // wave 0..3
    const int lane = t & 63;
    const int b    = bx * 4 + w;          // 512*4 = 2048 rows
    const float* xr = x + (size_t)b * K_DIM + lane * 8;
    float4 xa = *(const float4*)(xr);
    float4 xb = *(const float4*)(xr + 4);
    float xs[8] = {xa.x, xa.y, xa.z, xa.w, xb.x, xb.y, xb.z, xb.w};
    float m = xs[0];
#pragma unroll
    for (int i = 1; i < 8; ++i) m = fmaxf(m, xs[i]);
#pragma unroll
    for (int off = 32; off; off >>= 1) m = fmaxf(m, __shfl_xor(m, off));

    // ---- gate: wait for all 64 phase-A blocks ----
    while (__hip_atomic_load(flag, __ATOMIC_ACQUIRE,
                             __HIP_MEMORY_SCOPE_AGENT) < NWORK)
        __builtin_amdgcn_s_sleep(2);

    // ---- phase B: reduce W min/max, prune, gather candidates ----
    float bmin = ws[WS_PAIRS + 2 * lane];
    float bmax = ws[WS_PAIRS + 2 * lane + 1];
#pragma unroll
    for (int off = 32; off; off >>= 1) {
        bmin = fminf(bmin, __shfl_xor(bmin, off));
        bmax = fmaxf(bmax, __shfl_xor(bmax, off));
    }
    // exact bound: k with x[b,k] < m - (Wmax-Wmin) can never win for any o
    const float thr = m - (bmax - bmin);

    float acc[8];
#pragma unroll
    for (int i = 0; i < 8; ++i) acc[i] = -INFINITY;
    const int o0 = lane * 8;

#pragma unroll
    for (int s = 0; s < 8; ++s) {
        unsigned long long mask = __ballot(xs[s] >= thr);
        while (mask) {
            const int src = __ffsll(mask) - 1;
            mask &= mask - 1;
            const float xv = __shfl(xs[s], src);
            const int k = src * 8 + s;
            const float* wr = Wt + (size_t)k * O_DIM + o0;
            float4 wa = *(const float4*)(wr);
            float4 wb = *(const float4*)(wr + 4);
            acc[0] = fmaxf(acc[0], xv + wa.x);
            acc[1] = fmaxf(acc[1], xv + wa.y);
            acc[2] = fmaxf(acc[2], xv + wa.z);
            acc[3] = fmaxf(acc[3], xv + wa.w);
            acc[4] = fmaxf(acc[4], xv + wb.x);
            acc[5] = fmaxf(acc[5], xv + wb.y);
            acc[6] = fmaxf(acc[6], xv + wb.z);
            acc[7] = fmaxf(acc[7], xv + wb.w);
        }
    }

    float* op = out + (size_t)b * O_DIM + o0;
    *(float4*)(op)     = make_float4(acc[0], acc[1], acc[2], acc[3]);
    *(float4*)(op + 4) = make_float4(acc[4], acc[5], acc[6], acc[7]);
}

// ws-too-small fallback: plain full scan, correct for any input.
__global__ __launch_bounds__(256) void tropical_naive(
    const float* __restrict__ x, const float* __restrict__ W,
    float* __restrict__ out)
{
    const int b = blockIdx.x;
    const int t = threadIdx.x;
#pragma unroll
    for (int half = 0; half < 2; ++half) {
        const int o = t + half * 256;
        const float* wr = W + (size_t)o * K_DIM;
        const float* xr = x + (size_t)b * K_DIM;
        float acc = -INFINITY;
        for (int k = 0; k < K_DIM; ++k)
            acc = fmaxf(acc, xr[k] + wr[k]);
        out[(size_t)b * O_DIM + o] = acc;
    }
}

extern "C" void kernel_launch(void* const* d_in, const int* in_sizes, int n_in,
                              void* d_out, int out_size, void* d_ws, size_t ws_size,
                              hipStream_t stream) {
    const float* x = (const float*)d_in[0];   // (2048, 512)
    const float* W = (const float*)d_in[1];   // (512, 512)
    float* out = (float*)d_out;               // (2048, 512)

    if (ws_size >= WS_NEED_BYTES) {
        hipMemsetAsync(d_ws, 0, 4, stream);   // zero the gate flag
        tropical_fused<<<512, 256, 0, stream>>>(
            x, W, (float*)d_ws, out);
    } else {
        tropical_naive<<<B_ROWS, 256, 0, stream>>>(x, W, out);
    }
}

// Round 8
// 98.771 us; speedup vs baseline: 1.3528x; 1.3528x over previous
//
#include <hip/hip_runtime.h>
#include <math.h>

// Tropical (max-plus) matmul: out[b,o] = max_k ( x[b,k] + W[o,k] )
// x: (2048,512) f32, W: (512,512) f32, out: (2048,512) f32.
//
// R10 post-mortem: fused gate worked correctly but ALL 131072 threads spun
// on one agent-scope cacheline (~11 loads/cy vs ~1/cy service) -> the 64
// RELEASE RMWs ping-ponged against 2048 reader-waves; phase A stretched
// 3us -> 80us. VALUBusy 0.87% over 80us = pure spin.
// R11: (a) ONE spinner per block (t==0 + __syncthreads, the cooperative-
// groups pattern) with s_sleep(32) backoff -> 0.25 loads/cy aggregate,
// 40x less pressure; releases proceed. (b) drop the W transpose entirely:
// phase A = min/max only (64 blocks x 16KB); phase B gathers candidate
// COLUMNS of W directly (8 scalar loads @ 2KB stride per lane per
// candidate, ~190MB of L2-resident traffic ~ 6us at ~3 cand/row). ws need
// drops to 520B, LDS to ~32B.
// Exactness unchanged: k with x[b,k] < m_b - (Wmax-Wmin) can never win
// for any o; max over the surviving superset is bit-identical.

#define B_ROWS 2048
#define K_DIM  512
#define O_DIM  512

// ws float layout: [0] flag (memset to 0) | [2..129] 64 (min,max) pairs.
#define WS_PAIRS 2
#define WS_NEED_BYTES ((size_t)(WS_PAIRS + 128) * sizeof(float))
#define NWORK 64u

__global__ __launch_bounds__(256) void tropical_fused(
    const float* __restrict__ x, const float* __restrict__ W,
    float* __restrict__ ws, float* __restrict__ out)
{
    __shared__ float wmin4[4], wmax4[4];

    const int t  = threadIdx.x;
    const int bx = blockIdx.x;
    unsigned int* flag = (unsigned int*)ws;

    // ---- phase A: blocks 0..63 compute W block min/max (rows bx*8..+7) ----
    if (bx < 64) {
        const float* wbase = W + (size_t)bx * 8 * K_DIM;   // 16 KB slice
        float lmin = INFINITY, lmax = -INFINITY;
#pragma unroll
        for (int q = 0; q < 4; ++q) {
            float4 v = *(const float4*)(wbase + 4 * (t + 256 * q));
            lmin = fminf(lmin, fminf(fminf(v.x, v.y), fminf(v.z, v.w)));
            lmax = fmaxf(lmax, fmaxf(fmaxf(v.x, v.y), fmaxf(v.z, v.w)));
        }
#pragma unroll
        for (int off = 32; off; off >>= 1) {
            lmin = fminf(lmin, __shfl_xor(lmin, off));
            lmax = fmaxf(lmax, __shfl_xor(lmax, off));
        }
        if ((t & 63) == 0) { wmin4[t >> 6] = lmin; wmax4[t >> 6] = lmax; }
        __syncthreads();
        if (t == 0) {
            ws[WS_PAIRS + 2 * bx] =
                fminf(fminf(wmin4[0], wmin4[1]), fminf(wmin4[2], wmin4[3]));
            ws[WS_PAIRS + 2 * bx + 1] =
                fmaxf(fmaxf(wmax4[0], wmax4[1]), fmaxf(wmax4[2], wmax4[3]));
            __threadfence();              // pair visible before release
            __hip_atomic_fetch_add(flag, 1u, __ATOMIC_RELEASE,
                                   __HIP_MEMORY_SCOPE_AGENT);
        }
    }

    // ---- phase B preamble (ALL blocks, pre-gate): x row + row max ----
    const int w    = t >> 6;              // wave 0..3
    const int lane = t & 63;
    const int b    = bx * 4 + w;          // 512*4 = 2048 rows
    const float* xr = x + (size_t)b * K_DIM + lane * 8;
    float4 xa = *(const float4*)(xr);
    float4 xb = *(const float4*)(xr + 4);
    float xs[8] = {xa.x, xa.y, xa.z, xa.w, xb.x, xb.y, xb.z, xb.w};
    float m = xs[0];
#pragma unroll
    for (int i = 1; i < 8; ++i) m = fmaxf(m, xs[i]);
#pragma unroll
    for (int off = 32; off; off >>= 1) m = fmaxf(m, __shfl_xor(m, off));

    // ---- gate: one spinner per block, coarse backoff ----
    if (t == 0) {
        while (__hip_atomic_load(flag, __ATOMIC_ACQUIRE,
                                 __HIP_MEMORY_SCOPE_AGENT) < NWORK)
            __builtin_amdgcn_s_sleep(32);      // ~2k cy between probes
    }
    __syncthreads();   // t0's acquire invalidated this CU's L1 for the block

    // ---- phase B: W range, prune, gather candidate columns of W ----
    float bmin = ws[WS_PAIRS + 2 * lane];
    float bmax = ws[WS_PAIRS + 2 * lane + 1];
#pragma unroll
    for (int off = 32; off; off >>= 1) {
        bmin = fminf(bmin, __shfl_xor(bmin, off));
        bmax = fmaxf(bmax, __shfl_xor(bmax, off));
    }
    const float thr = m - (bmax - bmin);   // exact pruning bound

    float acc[8];
#pragma unroll
    for (int i = 0; i < 8; ++i) acc[i] = -INFINITY;
    const int o0 = lane * 8;

#pragma unroll
    for (int s = 0; s < 8; ++s) {
        unsigned long long mask = __ballot(xs[s] >= thr);
        while (mask) {
            const int src = __ffsll(mask) - 1;
            mask &= mask - 1;
            const float xv = __shfl(xs[s], src);
            const int k = src * 8 + s;
            const float* wc = W + (size_t)o0 * K_DIM + k;  // column k gather
            float wv[8];
#pragma unroll
            for (int i = 0; i < 8; ++i)
                wv[i] = wc[(size_t)i * K_DIM];
#pragma unroll
            for (int i = 0; i < 8; ++i)
                acc[i] = fmaxf(acc[i], xv + wv[i]);
        }
    }

    float* op = out + (size_t)b * O_DIM + o0;
    *(float4*)(op)     = make_float4(acc[0], acc[1], acc[2], acc[3]);
    *(float4*)(op + 4) = make_float4(acc[4], acc[5], acc[6], acc[7]);
}

// ws-too-small fallback: plain full scan, correct for any input.
__global__ __launch_bounds__(256) void tropical_naive(
    const float* __restrict__ x, const float* __restrict__ W,
    float* __restrict__ out)
{
    const int b = blockIdx.x;
    const int t = threadIdx.x;
#pragma unroll
    for (int half = 0; half < 2; ++half) {
        const int o = t + half * 256;
        const float* wr = W + (size_t)o * K_DIM;
        const float* xr = x + (size_t)b * K_DIM;
        float acc = -INFINITY;
        for (int k = 0; k < K_DIM; ++k)
            acc = fmaxf(acc, xr[k] + wr[k]);
        out[(size_t)b * O_DIM + o] = acc;
    }
}

extern "C" void kernel_launch(void* const* d_in, const int* in_sizes, int n_in,
                              void* d_out, int out_size, void* d_ws, size_t ws_size,
                              hipStream_t stream) {
    const float* x = (const float*)d_in[0];   // (2048, 512)
    const float* W = (const float*)d_in[1];   // (512, 512)
    float* out = (float*)d_out;               // (2048, 512)

    if (ws_size >= WS_NEED_BYTES) {
        hipMemsetAsync(d_ws, 0, 4, stream);   // zero the gate flag
        tropical_fused<<<512, 256, 0, stream>>>(
            x, W, (float*)d_ws, out);
    } else {
        tropical_naive<<<B_ROWS, 256, 0, stream>>>(x, W, out);
    }
}

// Round 9
// 97.963 us; speedup vs baseline: 1.3639x; 1.0083x over previous
//
#include <hip/hip_runtime.h>
#include <math.h>

// Tropical (max-plus) matmul: out[b,o] = max_k ( x[b,k] + W[o,k] )
// x: (2048,512) f32, W: (512,512) f32, out: (2048,512) f32.
//
// R11 post-mortem: gate cost halved with spinner count (80us @ 2048
// spinners -> 45.5us @ 512) -> the cost is 64 SERIALIZED fetch_adds on one
// cacheline against agent-scope reader traffic (~0.7us each), not the
// spin rate. VALUBusy 1.46% = phase B itself is ~1us of work; FETCH 6.2MB
// confirms the no-transpose column gather is fine.
// R12: no RMWs, no memset, ONE dispatch.
//  - phase-A block i release-stores pairs[i] (packed u64 min/max) then
//    flags[i] = MAGIC ^ i. Distinct addresses -> zero write serialization.
//  - gate: wave 0 probes all 64 flags with ONE per-lane acquire load +
//    __all(); s_sleep backoff.
//  - no-memset safety: the harness's per-iter ws fill can't forge 64
//    distinct MAGIC^i values (<=16B-periodic pattern matches <=4 slots);
//    if a fill is ever skipped, stale flags/pairs are bit-identical
//    (same W, deterministic) -> output unchanged. Exactness of pruning
//    unchanged: k with x[b,k] < m_b - (Wmax-Wmin) can never win any o.

#define B_ROWS 2048
#define K_DIM  512
#define O_DIM  512
#define MAGIC  0x9E3779B9u

// ws layout: u32 flags[64] @ byte 0 | u64 pairs[64] @ byte 256.
#define WS_NEED_BYTES 768

__global__ __launch_bounds__(256) void tropical_fused(
    const float* __restrict__ x, const float* __restrict__ W,
    unsigned int* __restrict__ ws, float* __restrict__ out)
{
    __shared__ float wmin4[4], wmax4[4];
    __shared__ float sg[2];               // broadcast gmin, gmax

    const int t  = threadIdx.x;
    const int bx = blockIdx.x;
    unsigned int* flags = ws;
    unsigned long long* pairs = (unsigned long long*)(ws + 64);  // byte 256

    // ---- phase A: blocks 0..63, W rows bx*8..+7 (16 KB) min/max ----
    if (bx < 64) {
        const float* wbase = W + (size_t)bx * 8 * K_DIM;
        float lmin = INFINITY, lmax = -INFINITY;
#pragma unroll
        for (int q = 0; q < 4; ++q) {
            float4 v = *(const float4*)(wbase + 4 * (t + 256 * q));
            lmin = fminf(lmin, fminf(fminf(v.x, v.y), fminf(v.z, v.w)));
            lmax = fmaxf(lmax, fmaxf(fmaxf(v.x, v.y), fmaxf(v.z, v.w)));
        }
#pragma unroll
        for (int off = 32; off; off >>= 1) {
            lmin = fminf(lmin, __shfl_xor(lmin, off));
            lmax = fmaxf(lmax, __shfl_xor(lmax, off));
        }
        if ((t & 63) == 0) { wmin4[t >> 6] = lmin; wmax4[t >> 6] = lmax; }
        __syncthreads();
        if (t == 0) {
            const float bmin =
                fminf(fminf(wmin4[0], wmin4[1]), fminf(wmin4[2], wmin4[3]));
            const float bmax =
                fmaxf(fmaxf(wmax4[0], wmax4[1]), fmaxf(wmax4[2], wmax4[3]));
            const unsigned long long pv =
                (unsigned long long)__float_as_uint(bmin) |
                ((unsigned long long)__float_as_uint(bmax) << 32);
            __hip_atomic_store(&pairs[bx], pv, __ATOMIC_RELEASE,
                               __HIP_MEMORY_SCOPE_AGENT);
            __hip_atomic_store(&flags[bx], MAGIC ^ (unsigned)bx,
                               __ATOMIC_RELEASE, __HIP_MEMORY_SCOPE_AGENT);
        }
    }

    // ---- phase B preamble (ALL blocks, pre-gate): x row + row max ----
    const int w    = t >> 6;              // wave 0..3
    const int lane = t & 63;
    const int b    = bx * 4 + w;          // 512*4 = 2048 rows
    const float* xr = x + (size_t)b * K_DIM + lane * 8;
    float4 xa = *(const float4*)(xr);
    float4 xb = *(const float4*)(xr + 4);
    float xs[8] = {xa.x, xa.y, xa.z, xa.w, xb.x, xb.y, xb.z, xb.w};
    float m = xs[0];
#pragma unroll
    for (int i = 1; i < 8; ++i) m = fmaxf(m, xs[i]);
#pragma unroll
    for (int off = 32; off; off >>= 1) m = fmaxf(m, __shfl_xor(m, off));

    // ---- gate: wave 0, one per-lane acquire load per probe, no RMWs ----
    if (t < 64) {
        for (;;) {
            const unsigned int v = __hip_atomic_load(
                &flags[t], __ATOMIC_ACQUIRE, __HIP_MEMORY_SCOPE_AGENT);
            if (__all(v == (MAGIC ^ (unsigned)t))) break;
            __builtin_amdgcn_s_sleep(16);          // ~1k cy backoff
        }
        // pairs: lane l reads pair l (acquire), wave-reduce to global range
        const unsigned long long pv = __hip_atomic_load(
            &pairs[t], __ATOMIC_ACQUIRE, __HIP_MEMORY_SCOPE_AGENT);
        float gmin = __uint_as_float((unsigned int)(pv & 0xffffffffu));
        float gmax = __uint_as_float((unsigned int)(pv >> 32));
#pragma unroll
        for (int off = 32; off; off >>= 1) {
            gmin = fminf(gmin, __shfl_xor(gmin, off));
            gmax = fmaxf(gmax, __shfl_xor(gmax, off));
        }
        if (t == 0) { sg[0] = gmin; sg[1] = gmax; }
    }
    __syncthreads();

    // ---- phase B: prune + gather candidate columns of W ----
    const float thr = m - (sg[1] - sg[0]);   // exact bound; >=1 candidate

    float acc[8];
#pragma unroll
    for (int i = 0; i < 8; ++i) acc[i] = -INFINITY;
    const int o0 = lane * 8;

#pragma unroll
    for (int s = 0; s < 8; ++s) {
        unsigned long long mask = __ballot(xs[s] >= thr);
        while (mask) {
            const int src = __ffsll(mask) - 1;
            mask &= mask - 1;
            const float xv = __shfl(xs[s], src);
            const int k = src * 8 + s;
            const float* wc = W + (size_t)o0 * K_DIM + k;  // column k gather
            float wv[8];
#pragma unroll
            for (int i = 0; i < 8; ++i)
                wv[i] = wc[(size_t)i * K_DIM];
#pragma unroll
            for (int i = 0; i < 8; ++i)
                acc[i] = fmaxf(acc[i], xv + wv[i]);
        }
    }

    float* op = out + (size_t)b * O_DIM + o0;
    *(float4*)(op)     = make_float4(acc[0], acc[1], acc[2], acc[3]);
    *(float4*)(op + 4) = make_float4(acc[4], acc[5], acc[6], acc[7]);
}

// ws-too-small fallback: plain full scan, correct for any input.
__global__ __launch_bounds__(256) void tropical_naive(
    const float* __restrict__ x, const float* __restrict__ W,
    float* __restrict__ out)
{
    const int b = blockIdx.x;
    const int t = threadIdx.x;
#pragma unroll
    for (int half = 0; half < 2; ++half) {
        const int o = t + half * 256;
        const float* wr = W + (size_t)o * K_DIM;
        const float* xr = x + (size_t)b * K_DIM;
        float acc = -INFINITY;
        for (int k = 0; k < K_DIM; ++k)
            acc = fmaxf(acc, xr[k] + wr[k]);
        out[(size_t)b * O_DIM + o] = acc;
    }
}

extern "C" void kernel_launch(void* const* d_in, const int* in_sizes, int n_in,
                              void* d_out, int out_size, void* d_ws, size_t ws_size,
                              hipStream_t stream) {
    const float* x = (const float*)d_in[0];   // (2048, 512)
    const float* W = (const float*)d_in[1];   // (512, 512)
    float* out = (float*)d_out;               // (2048, 512)

    if (ws_size >= WS_NEED_BYTES) {
        tropical_fused<<<512, 256, 0, stream>>>(
            x, W, (unsigned int*)d_ws, out);
    } else {
        tropical_naive<<<B_ROWS, 256, 0, stream>>>(x, W, out);
    }
}

// Round 10
// 65.350 us; speedup vs baseline: 2.0446x; 1.4991x over previous
//
#include <hip/hip_runtime.h>
#include <math.h>

// Tropical (max-plus) matmul: out[b,o] = max_k ( x[b,k] + W[o,k] )
// x: (2048,512) f32, W: (512,512) f32, out: (2048,512) f32.
//
// R12 post-mortem: zero-RMW gate == RMW gate == ~46-48us -> gate-mechanism
// theories falsified. Unifying model: the harness's 268MB ws poison fill
// (~42us, in-stream before us) leaves L2 full of dirty lines whose HBM
// write-back drains DURING our kernel; cold reads are throttled to a few
// hundred GB/s. Any single fused dispatch holds all waves inside that
// starved window (R10-R12: 133/98/98us e2e). The empirical best under the
// drain is the R9 two-kernel structure (65.3us e2e): tiny prep kernel
// (W transpose + min/max, 2MB), then a sparse kernel whose Wt gather is
// coalesced and L2-hot. Restore it verbatim (bit-exact, absmax 0.0).
//
// Exactness: k with x[b,k] < m_b - (Wmax - Wmin) satisfies
// x[b,k] + W[o,k] < m_b + Wmin <= x[b,k*] + W[o,k*] for every o, so
// max over the surviving candidate superset is bit-identical to the full
// scan; any candidate count is handled (worst case = full scan).

#define B_ROWS 2048
#define K_DIM  512
#define O_DIM  512

// ws layout (floats): [0..127] 64 (min,max) pairs; Wt at float offset 256.
#define WS_WT_OFF 256
#define WS_NEED_BYTES ((size_t)(WS_WT_OFF + K_DIM * O_DIM) * sizeof(float))

__global__ __launch_bounds__(256) void prep_transpose_minmax(
    const float* __restrict__ W, float* __restrict__ ws)
{
    __shared__ float sm[64][65];      // 64x64 tile, padded
    __shared__ float wmin[4], wmax[4];

    const int t  = threadIdx.x;
    const int bx = blockIdx.x;        // 64 blocks: 8x8 tiles of 64x64
    const int tr = (bx >> 3) * 64;    // o-dim (W row) tile base
    const int tc = (bx & 7) * 64;     // k-dim (W col) tile base

    const int lr0 = t >> 4;           // 0..15
    const int lc  = (t & 15) * 4;     // 0..60

    float lmin = INFINITY, lmax = -INFINITY;
#pragma unroll
    for (int q = 0; q < 4; ++q) {
        const int r = lr0 + q * 16;
        float4 v = *(const float4*)(W + (size_t)(tr + r) * K_DIM + tc + lc);
        sm[r][lc + 0] = v.x; sm[r][lc + 1] = v.y;
        sm[r][lc + 2] = v.z; sm[r][lc + 3] = v.w;
        lmin = fminf(lmin, fminf(fminf(v.x, v.y), fminf(v.z, v.w)));
        lmax = fmaxf(lmax, fmaxf(fmaxf(v.x, v.y), fmaxf(v.z, v.w)));
    }
    __syncthreads();

    // transposed write: Wt[k][o]
    float* Wt = ws + WS_WT_OFF;
#pragma unroll
    for (int q = 0; q < 4; ++q) {
        const int kr = lr0 + q * 16;
        float4 v;
        v.x = sm[lc + 0][kr]; v.y = sm[lc + 1][kr];
        v.z = sm[lc + 2][kr]; v.w = sm[lc + 3][kr];
        *(float4*)(Wt + (size_t)(tc + kr) * O_DIM + tr + lc) = v;
    }

    // block min/max -> ws[2*bx], ws[2*bx+1]
#pragma unroll
    for (int off = 32; off; off >>= 1) {
        lmin = fminf(lmin, __shfl_xor(lmin, off));
        lmax = fmaxf(lmax, __shfl_xor(lmax, off));
    }
    if ((t & 63) == 0) { wmin[t >> 6] = lmin; wmax[t >> 6] = lmax; }
    __syncthreads();
    if (t == 0) {
        ws[2 * bx]     = fminf(fminf(wmin[0], wmin[1]), fminf(wmin[2], wmin[3]));
        ws[2 * bx + 1] = fmaxf(fmaxf(wmax[0], wmax[1]), fmaxf(wmax[2], wmax[3]));
    }
}

__global__ __launch_bounds__(256) void tropical_sparse(
    const float* __restrict__ x, const float* __restrict__ ws,
    float* __restrict__ out)
{
    const int t    = threadIdx.x;
    const int w    = t >> 6;                  // wave 0..3
    const int lane = t & 63;
    const int b    = blockIdx.x * 4 + w;      // row, 512 blocks x 4 = 2048
    const float* Wt = ws + WS_WT_OFF;

    // x row: 8 consecutive floats per lane (k = lane*8 .. +7)
    const float* xr = x + (size_t)b * K_DIM + lane * 8;
    float4 xa = *(const float4*)(xr);
    float4 xb = *(const float4*)(xr + 4);
    float xs[8] = {xa.x, xa.y, xa.z, xa.w, xb.x, xb.y, xb.z, xb.w};

    // global W min/max from the 64 per-block pairs (lane l reads pair l)
    float bmin = ws[2 * lane], bmax = ws[2 * lane + 1];
#pragma unroll
    for (int off = 32; off; off >>= 1) {
        bmin = fminf(bmin, __shfl_xor(bmin, off));
        bmax = fmaxf(bmax, __shfl_xor(bmax, off));
    }
    const float dW = bmax - bmin;

    // row max
    float m = xs[0];
#pragma unroll
    for (int i = 1; i < 8; ++i) m = fmaxf(m, xs[i]);
#pragma unroll
    for (int off = 32; off; off >>= 1) m = fmaxf(m, __shfl_xor(m, off));
    const float thr = m - dW;

    float acc[8];
#pragma unroll
    for (int i = 0; i < 8; ++i) acc[i] = -INFINITY;

    const int o0 = lane * 8;
    // candidates: any k with x[b,k] >= thr (>=1 exists: the argmax itself)
#pragma unroll
    for (int s = 0; s < 8; ++s) {
        unsigned long long mask = __ballot(xs[s] >= thr);
        while (mask) {
            const int src = __ffsll(mask) - 1;
            mask &= mask - 1;
            const float xv = __shfl(xs[s], src);
            const int k = src * 8 + s;
            const float* wr = Wt + (size_t)k * O_DIM + o0;   // coalesced, L2-hot
            float4 wa = *(const float4*)(wr);
            float4 wb = *(const float4*)(wr + 4);
            acc[0] = fmaxf(acc[0], xv + wa.x);
            acc[1] = fmaxf(acc[1], xv + wa.y);
            acc[2] = fmaxf(acc[2], xv + wa.z);
            acc[3] = fmaxf(acc[3], xv + wa.w);
            acc[4] = fmaxf(acc[4], xv + wb.x);
            acc[5] = fmaxf(acc[5], xv + wb.y);
            acc[6] = fmaxf(acc[6], xv + wb.z);
            acc[7] = fmaxf(acc[7], xv + wb.w);
        }
    }

    float* op = out + (size_t)b * O_DIM + o0;
    *(float4*)(op)     = make_float4(acc[0], acc[1], acc[2], acc[3]);
    *(float4*)(op + 4) = make_float4(acc[4], acc[5], acc[6], acc[7]);
}

// ws-too-small fallback: plain full scan, correct for any input.
__global__ __launch_bounds__(256) void tropical_naive(
    const float* __restrict__ x, const float* __restrict__ W,
    float* __restrict__ out)
{
    const int b = blockIdx.x;
    const int t = threadIdx.x;
#pragma unroll
    for (int half = 0; half < 2; ++half) {
        const int o = t + half * 256;
        const float* wr = W + (size_t)o * K_DIM;
        const float* xr = x + (size_t)b * K_DIM;
        float acc = -INFINITY;
        for (int k = 0; k < K_DIM; ++k)
            acc = fmaxf(acc, xr[k] + wr[k]);
        out[(size_t)b * O_DIM + o] = acc;
    }
}

extern "C" void kernel_launch(void* const* d_in, const int* in_sizes, int n_in,
                              void* d_out, int out_size, void* d_ws, size_t ws_size,
                              hipStream_t stream) {
    const float* x = (const float*)d_in[0];   // (2048, 512)
    const float* W = (const float*)d_in[1];   // (512, 512)
    float* out = (float*)d_out;               // (2048, 512)

    if (ws_size >= WS_NEED_BYTES) {
        prep_transpose_minmax<<<64, 256, 0, stream>>>(W, (float*)d_ws);
        tropical_sparse<<<B_ROWS / 4, 256, 0, stream>>>(
            x, (const float*)d_ws, out);
    } else {
        tropical_naive<<<B_ROWS, 256, 0, stream>>>(x, W, out);
    }
}